// Round 8
// baseline (102.892 us; speedup 1.0000x reference)
//
#include <hip/hip_runtime.h>

#define N_NETS  131072
#define N_PINS  (N_NETS * 4)
#define N_NODES 55000
#define NRECMAX (N_NETS + 128)     // nets + macro slots (96 used)
#define NBBLK   129                // ceil(NRECMAX/1024)
#define NPARTS  8
#define BKTCAP  16384              // entries per slab bucket (max slab ~8300)
#define STCAP   128                // per-block per-bucket staging (avg ~36)

struct __align__(16) Meta { uint2 cols; float2 whv; float4 pys; };  // 32B

// Per-record deposit data
__device__ uint4 g_pair[NRECMAX * 2];  // {roww(lo16=r0,hi16=r0+1), px0, px1, pad}
__device__ Meta  g_meta[NRECMAX];
__device__ unsigned g_bkt[64 * BKTCAP];              // slab buckets: (i<<1)|pair
__device__ float g_part[NPARTS * 512 * 1024];        // per-part y-scanned tiles
                                                     // layout [p][x][2*y+map]

// d_ws layout: u32 bcnt[64] @0; int cnt2[2] @256; int tick @264  (memset to 0)

__global__ __launch_bounds__(1024) void k_bbox(
    const float* __restrict__ pos, const float* __restrict__ pin_pos,
    const float* __restrict__ nsx, const float* __restrict__ nsy,
    const float* __restrict__ nw,  const int* __restrict__ fnp,
    const int* __restrict__ mid, int nm, unsigned* __restrict__ bcnt)
{
    __shared__ unsigned s_stage[64 * STCAP];
    __shared__ int s_cnt[64];
    __shared__ unsigned s_base[64];
    int tid = threadIdx.x;
    int t = blockIdx.x * 1024 + tid;
    if (tid < 64) s_cnt[tid] = 0;
    __syncthreads();

    auto append = [&](int s, unsigned ent) {
        int off = atomicAdd(&s_cnt[s], 1);
        if (off < STCAP) s_stage[s * STCAP + off] = ent;
        else {
            unsigned g = atomicAdd(&bcnt[s], 1u);
            if (g < BKTCAP) g_bkt[s * BKTCAP + g] = ent;
        }
    };

    bool valid = t < N_NETS + nm && t < NRECMAX;
    if (valid) {
        float xmin, xmax, ymin, ymax, wh, wv;
        if (t < N_NETS) {
            int4 p = ((const int4*)fnp)[t];
            float x0 = pin_pos[p.x], x1 = pin_pos[p.y], x2 = pin_pos[p.z], x3 = pin_pos[p.w];
            float y0 = pin_pos[N_PINS + p.x], y1 = pin_pos[N_PINS + p.y];
            float y2 = pin_pos[N_PINS + p.z], y3 = pin_pos[N_PINS + p.w];
            xmin = fminf(fminf(x0, x1), fminf(x2, x3));
            xmax = fmaxf(fmaxf(x0, x1), fmaxf(x2, x3));
            ymin = fminf(fminf(y0, y1), fminf(y2, y3));
            ymax = fmaxf(fmaxf(y0, y1), fmaxf(y2, y3));
            float w = nw[t];
            wh = w / (ymax - ymin);
            wv = w / (xmax - xmin);
        } else {
            int idx = mid[t - N_NETS];
            xmin = pos[idx]; ymin = pos[N_NODES + idx];
            float sx = nsx[idx], sy = nsy[idx];
            xmax = xmin + sx; ymax = ymin + sy;
            wh = wv = 10.0f / (sx * sy);
        }
        const float B = 1.0f / 512.0f;
        int xl = min(max((int)(xmin * 512.0f), 0), 511);
        int xh = min(max((int)(xmax * 512.0f), 0), 511);
        int yl = min(max((int)(ymin * 512.0f), 0), 511);
        int yh = min(max((int)(ymax * 512.0f), 0), 511);
        g_pair[2 * t] = make_uint4(
            (unsigned)xl | ((unsigned)(xl + 1) << 16),
            __float_as_uint((xl + 1) * B - xmin),
            __float_as_uint(xmin - xl * B), 0u);
        g_pair[2 * t + 1] = make_uint4(
            (unsigned)xh | ((unsigned)(xh + 1) << 16),
            __float_as_uint(xmax - (xh + 1) * B),
            __float_as_uint(xh * B - xmax), 0u);
        Meta m;
        m.cols = make_uint2((unsigned)yl | ((unsigned)(yl + 1) << 16),
                            (unsigned)yh | ((unsigned)(yh + 1) << 16));
        m.whv = make_float2(wh, wv);
        m.pys = make_float4((yl + 1) * B - ymin, ymin - yl * B,
                            ymax - (yh + 1) * B, yh * B - ymax);
        g_meta[t] = m;
        int s0 = xl >> 3, s1 = (xl + 1) >> 3, s2 = xh >> 3, s3 = (xh + 1) >> 3;
        append(s0, ((unsigned)t << 1));
        if (s1 != s0 && xl + 1 < 512) append(s1, ((unsigned)t << 1));
        append(s2, ((unsigned)t << 1) | 1u);
        if (s3 != s2 && xh + 1 < 512) append(s3, ((unsigned)t << 1) | 1u);
    }
    __syncthreads();
    if (tid < 64) s_base[tid] = atomicAdd(&bcnt[tid], (unsigned)min(s_cnt[tid], STCAP));
    __syncthreads();
    int wid = tid >> 6, lane = tid & 63;
    for (int s = wid; s < 64; s += 16) {
        int n = min(s_cnt[s], STCAP);
        unsigned b = s_base[s];
        for (int k = lane; k < n; k += 64) {
            unsigned g = b + (unsigned)k;
            if (g < BKTCAP) g_bkt[s * BKTCAP + g] = s_stage[s * STCAP + k];
        }
    }
}

// 512 blocks = 8 parts x 64 slabs (part-major order: all slabs' part-0 first).
// 2 blocks/CU resident -> slab-0 stragglers co-schedule with short blocks.
__global__ __launch_bounds__(1024) void k_deposit(const unsigned* __restrict__ bcnt) {
    __shared__ float tile[8706];           // 8 rows x 1024 interleaved + dummy @8192
    int tid = threadIdx.x;
    int s = blockIdx.x & 63, p = blockIdx.x >> 6;
    unsigned rowlo = (unsigned)(s * 8);
#pragma unroll
    for (int k = tid; k < 8706; k += 1024) tile[k] = 0.0f;
    __syncthreads();

    int cnt = min((int)bcnt[s], BKTCAP);
    int lo = (cnt * p) >> 3, hi = (cnt * (p + 1)) >> 3;
    for (int k = lo + tid; k < hi; k += 1024) {
        unsigned ent = g_bkt[s * BKTCAP + k];
        int i = (int)(ent >> 1), pr = (int)(ent & 1u);
        uint4 pw = g_pair[2 * i + pr];
        unsigned roww = pw.x;
        float px0 = __uint_as_float(pw.y), px1 = __uint_as_float(pw.z);
        Meta m = g_meta[i];
        unsigned c0 = m.cols.x & 0xFFFFu, c1 = m.cols.x >> 16;
        unsigned c2 = m.cols.y & 0xFFFFu, c3 = m.cols.y >> 16;
        int r0 = (int)(roww & 0xFFFFu);
#pragma unroll
        for (int rr = 0; rr < 2; ++rr) {
            unsigned rel = (unsigned)(r0 + rr) - rowlo;
            if (rel < 8u) {
                float px = rr ? px1 : px0;
                float ah = px * m.whv.x, av = px * m.whv.y;
                int base = (int)rel * 1024;
                int i0 = (c0 < 512u) ? base + 2 * (int)c0 : 8192;
                int i1 = (c1 < 512u) ? base + 2 * (int)c1 : 8192;
                int i2 = (c2 < 512u) ? base + 2 * (int)c2 : 8192;
                int i3 = (c3 < 512u) ? base + 2 * (int)c3 : 8192;
                unsafeAtomicAdd(&tile[i0],     ah * m.pys.x);
                unsafeAtomicAdd(&tile[i0 + 1], av * m.pys.x);
                unsafeAtomicAdd(&tile[i1],     ah * m.pys.y);
                unsafeAtomicAdd(&tile[i1 + 1], av * m.pys.y);
                unsafeAtomicAdd(&tile[i2],     ah * m.pys.z);
                unsafeAtomicAdd(&tile[i2 + 1], av * m.pys.z);
                unsafeAtomicAdd(&tile[i3],     ah * m.pys.w);
                unsafeAtomicAdd(&tile[i3 + 1], av * m.pys.w);
            }
        }
    }
    __syncthreads();

    // y-scan: 8 waves, wave r scans row r as float2 (H,V together), carry chain
    int wid = tid >> 6, lane = tid & 63;
    if (wid < 8) {
        float2* rowp = (float2*)&tile[wid * 1024];
        float cx = 0.0f, cy = 0.0f;
        for (int ch = 0; ch < 8; ++ch) {
            float2 v = rowp[ch * 64 + lane];
#pragma unroll
            for (int off = 1; off < 64; off <<= 1) {
                float tx = __shfl_up(v.x, off);
                float ty = __shfl_up(v.y, off);
                if (lane >= off) { v.x += tx; v.y += ty; }
            }
            v.x += cx; v.y += cy;
            rowp[ch * 64 + lane] = v;
            cx = __shfl(v.x, 63); cy = __shfl(v.y, 63);
        }
    }
    __syncthreads();
    int dst = p * 524288 + (int)rowlo * 1024;
#pragma unroll
    for (int k = 0; k < 8; ++k) {
        int idx = tid + k * 1024;
        g_part[dst + idx] = tile[idx];
    }
}

// 64 blocks, block b owns output cols y in [8b, 8b+8). Part-merge + y-blur
// (shfl) -> LDS; per-wave x-scan + in-register x-blur; map/counts; ticket.
__global__ __launch_bounds__(1024) void k_finish(float* __restrict__ out,
                                                 int* __restrict__ cnt2,
                                                 int* __restrict__ tick) {
    __shared__ float sB[16 * 512];
    int tid = threadIdx.x;
    int b = blockIdx.x;
    int lane = tid & 63;
    int c20 = tid & 31;
    int xg = tid >> 5;
    int jj = (c20 < 10) ? c20 : c20 - 10;
    int cy = 8 * b - 1 + jj;
    if (cy < 0) cy = 1;
    if (cy > 511) cy = 510;
    int map = (c20 < 10) ? 0 : 1;
    int gcol = 2 * cy + map;                // interleaved column
    const float kw  = expf(-0.5f / 1024.0f);
    const float k1n = 1.0f / (1.0f + 2.0f * kw);
    const float k0n = kw * k1n;
    const float scale = 262144.0f / 50000.0f;
    bool active = c20 < 20;
    int t8  = (c20 < 10) ? c20 - 1 : c20 - 11;

    for (int xo = 0; xo < 16; ++xo) {
        int x = xo * 32 + xg;
        float v = 0.0f;
        if (active) {
            int base = x * 1024 + gcol;
#pragma unroll
            for (int p = 0; p < NPARTS; ++p) v += g_part[p * 524288 + base];
        }
        float vm = __shfl(v, lane - 1);
        float vp = __shfl(v, lane + 1);
        float yb = (k0n * (vm + vp) + k1n * v) * scale;
        if (t8 >= 0 && t8 < 8) sB[(map * 8 + t8) * 512 + x] = yb;
    }
    __syncthreads();

    int w = tid >> 6;
    float s0,s1,s2,s3,s4,s5,s6,s7;
    {
        float4 a  = *(float4*)&sB[w * 512 + lane * 8];
        float4 bq = *(float4*)&sB[w * 512 + lane * 8 + 4];
        s0 = a.x; s1 = s0 + a.y; s2 = s1 + a.z; s3 = s2 + a.w;
        s4 = s3 + bq.x; s5 = s4 + bq.y; s6 = s5 + bq.z; s7 = s6 + bq.w;
        float tot = s7;
#pragma unroll
        for (int off = 1; off < 64; off <<= 1) {
            float tv = __shfl_up(tot, off);
            if (lane >= off) tot += tv;
        }
        float e = tot - s7;
        s0 += e; s1 += e; s2 += e; s3 += e; s4 += e; s5 += e; s6 += e; s7 += e;
    }
    {
        float prev = __shfl(s7, lane - 1);
        float next = __shfl(s0, lane + 1);
        float pm = (lane == 0) ? s1 : prev;
        float nx = (lane == 63) ? s6 : next;
        float b0 = k0n * (pm + s1) + k1n * s0;
        float b1 = k0n * (s0 + s2) + k1n * s1;
        float b2 = k0n * (s1 + s3) + k1n * s2;
        float b3 = k0n * (s2 + s4) + k1n * s3;
        float b4 = k0n * (s3 + s5) + k1n * s4;
        float b5 = k0n * (s4 + s6) + k1n * s5;
        float b6 = k0n * (s5 + s7) + k1n * s6;
        float b7 = k0n * (s6 + nx) + k1n * s7;
        float* row = &sB[w * 512 + lane * 8];
        row[0]=b0; row[1]=b1; row[2]=b2; row[3]=b3;
        row[4]=b4; row[5]=b5; row[6]=b6; row[7]=b7;
    }
    __syncthreads();

    int x = tid >> 1, qh = (tid & 1) * 4;
    float4 o;
    int ch = 0, cv = 0;
#pragma unroll
    for (int k = 0; k < 4; ++k) {
        int tt = qh + k;
        float hv = sB[tt * 512 + x];
        float vv = sB[(8 + tt) * 512 + x];
        ((float*)&o)[k] = fmaxf(fabsf(hv), fabsf(vv));
        ch += (hv > 1.0f); cv += (vv > 1.0f);
    }
    *(float4*)&out[x * 512 + 8 * b + qh] = o;
#pragma unroll
    for (int off = 32; off > 0; off >>= 1) {
        ch += __shfl_down(ch, off);
        cv += __shfl_down(cv, off);
    }
    __shared__ int scnt[2];
    if (tid < 2) scnt[tid] = 0;
    __syncthreads();
    if (lane == 0) { atomicAdd(&scnt[0], ch); atomicAdd(&scnt[1], cv); }
    __syncthreads();
    if (tid == 0) {
        atomicAdd(&cnt2[0], scnt[0]);
        atomicAdd(&cnt2[1], scnt[1]);
        __threadfence();
        int old = atomicAdd(tick, 1);
        if (old == 63) {
            __threadfence();
            int h = cnt2[0], v = cnt2[1];
            out[262144] = (float)((h > v) ? h : v);   // max_overflow
            out[262145] = (float)(h + v);             // total_overflow
        }
    }
}

extern "C" void kernel_launch(void* const* d_in, const int* in_sizes, int n_in,
                              void* d_out, int out_size, void* d_ws, size_t ws_size,
                              hipStream_t stream) {
    const float* pos     = (const float*)d_in[0];
    const float* pin_pos = (const float*)d_in[1];
    const float* nsx     = (const float*)d_in[2];
    const float* nsy     = (const float*)d_in[3];
    const float* nw      = (const float*)d_in[4];
    const int*   fnp     = (const int*)d_in[5];
    const int*   mid     = (const int*)d_in[6];
    int nm = in_sizes[6];
    float* out = (float*)d_out;
    unsigned* bcnt = (unsigned*)d_ws;
    int* cnt2 = (int*)((char*)d_ws + 256);
    int* tick = (int*)((char*)d_ws + 264);

    hipMemsetAsync(d_ws, 0, 512, stream);
    hipLaunchKernelGGL(k_bbox,    dim3(NBBLK), dim3(1024), 0, stream,
                       pos, pin_pos, nsx, nsy, nw, fnp, mid, nm, bcnt);
    hipLaunchKernelGGL(k_deposit, dim3(512), dim3(1024), 0, stream, bcnt);
    hipLaunchKernelGGL(k_finish,  dim3(64), dim3(1024), 0, stream, out, cnt2, tick);
}

// Round 9
// 68.198 us; speedup vs baseline: 1.5087x; 1.5087x over previous
//
#include <hip/hip_runtime.h>

#define N_NETS  131072
#define N_PINS  (N_NETS * 4)
#define N_NODES 55000
#define NRECMAX (N_NETS + 128)     // nets + macro slots (96 used)
#define NBBLK   129                // ceil(NRECMAX/1024)
#define NPARTS  4
#define BKTCAP  16384              // entries per slab bucket (avg ~8.7K, uniform)
#define STCAP   128                // per-block per-bucket staging (avg ~64)

struct __align__(16) Meta { uint2 cols; float2 whv; float4 pys; };  // 32B

// Per-record deposit data
__device__ uint4 g_pair[NRECMAX * 2];  // {roww(lo16=r0,hi16=r0+1), px0, px1, pad}
__device__ Meta  g_meta[NRECMAX];
__device__ unsigned g_bkt[64 * BKTCAP];              // entries: (i<<2)|edge
__device__ float g_part[NPARTS * 512 * 1024];        // per-part y-scanned tiles
                                                     // layout [p][x][2*y+map]

// d_ws layout: u32 bcnt[64] @0; int cnt2[2] @256; int tick @264  (memset to 0)

__global__ __launch_bounds__(1024) void k_bbox(
    const float* __restrict__ pos, const float* __restrict__ pin_pos,
    const float* __restrict__ nsx, const float* __restrict__ nsy,
    const float* __restrict__ nw,  const int* __restrict__ fnp,
    const int* __restrict__ mid, int nm, unsigned* __restrict__ bcnt)
{
    __shared__ unsigned s_stage[64 * STCAP];
    __shared__ int s_cnt[64];
    __shared__ unsigned s_base[64];
    int tid = threadIdx.x;
    int t = blockIdx.x * 1024 + tid;
    if (tid < 64) s_cnt[tid] = 0;
    __syncthreads();

    auto append = [&](int s, unsigned ent) {
        int off = atomicAdd(&s_cnt[s], 1);
        if (off < STCAP) s_stage[s * STCAP + off] = ent;
        else {
            unsigned g = atomicAdd(&bcnt[s], 1u);
            if (g < BKTCAP) g_bkt[s * BKTCAP + g] = ent;
        }
    };

    bool valid = t < N_NETS + nm && t < NRECMAX;
    if (valid) {
        float xmin, xmax, ymin, ymax, wh, wv;
        if (t < N_NETS) {
            int4 p = ((const int4*)fnp)[t];
            float x0 = pin_pos[p.x], x1 = pin_pos[p.y], x2 = pin_pos[p.z], x3 = pin_pos[p.w];
            float y0 = pin_pos[N_PINS + p.x], y1 = pin_pos[N_PINS + p.y];
            float y2 = pin_pos[N_PINS + p.z], y3 = pin_pos[N_PINS + p.w];
            xmin = fminf(fminf(x0, x1), fminf(x2, x3));
            xmax = fmaxf(fmaxf(x0, x1), fmaxf(x2, x3));
            ymin = fminf(fminf(y0, y1), fminf(y2, y3));
            ymax = fmaxf(fmaxf(y0, y1), fmaxf(y2, y3));
            float w = nw[t];
            wh = w / (ymax - ymin);
            wv = w / (xmax - xmin);
        } else {
            int idx = mid[t - N_NETS];
            xmin = pos[idx]; ymin = pos[N_NODES + idx];
            float sx = nsx[idx], sy = nsy[idx];
            xmax = xmin + sx; ymax = ymin + sy;
            wh = wv = 10.0f / (sx * sy);
        }
        const float B = 1.0f / 512.0f;
        int xl = min(max((int)(xmin * 512.0f), 0), 511);
        int xh = min(max((int)(xmax * 512.0f), 0), 511);
        int yl = min(max((int)(ymin * 512.0f), 0), 511);
        int yh = min(max((int)(ymax * 512.0f), 0), 511);
        g_pair[2 * t] = make_uint4(
            (unsigned)xl | ((unsigned)(xl + 1) << 16),
            __float_as_uint((xl + 1) * B - xmin),
            __float_as_uint(xmin - xl * B), 0u);
        g_pair[2 * t + 1] = make_uint4(
            (unsigned)xh | ((unsigned)(xh + 1) << 16),
            __float_as_uint(xmax - (xh + 1) * B),
            __float_as_uint(xh * B - xmax), 0u);
        Meta m;
        m.cols = make_uint2((unsigned)yl | ((unsigned)(yl + 1) << 16),
                            (unsigned)yh | ((unsigned)(yh + 1) << 16));
        m.whv = make_float2(wh, wv);
        m.pys = make_float4((yl + 1) * B - ymin, ymin - yl * B,
                            ymax - (yh + 1) * B, yh * B - ymax);
        g_meta[t] = m;
        // Row-permuted slab assignment: slab(r) = r & 63 -> uniform load.
        // One entry per x-edge (exactly one row each, 8 ds_add).
        append(xl & 63,        ((unsigned)t << 2) | 0u);
        if (xl + 1 < 512) append((xl + 1) & 63, ((unsigned)t << 2) | 1u);
        append(xh & 63,        ((unsigned)t << 2) | 2u);
        if (xh + 1 < 512) append((xh + 1) & 63, ((unsigned)t << 2) | 3u);
    }
    __syncthreads();
    if (tid < 64) s_base[tid] = atomicAdd(&bcnt[tid], (unsigned)min(s_cnt[tid], STCAP));
    __syncthreads();
    int wid = tid >> 6, lane = tid & 63;
    for (int s = wid; s < 64; s += 16) {
        int n = min(s_cnt[s], STCAP);
        unsigned b = s_base[s];
        for (int k = lane; k < n; k += 64) {
            unsigned g = b + (unsigned)k;
            if (g < BKTCAP) g_bkt[s * BKTCAP + g] = s_stage[s * STCAP + k];
        }
    }
}

// 256 blocks = 64 slabs x 4 parts (slab-major). Slab s holds global rows
// {s, s+64, ..., s+448} (row-permute -> uniform per-slab entry count).
__global__ __launch_bounds__(1024) void k_deposit(const unsigned* __restrict__ bcnt) {
    __shared__ float tile[8706];           // 8 rows x 1024 interleaved + dummy @8192
    int tid = threadIdx.x;
    int s = blockIdx.x >> 2, p = blockIdx.x & 3;
#pragma unroll
    for (int k = tid; k < 8706; k += 1024) tile[k] = 0.0f;
    __syncthreads();

    int cnt = min((int)bcnt[s], BKTCAP);
    int lo = (cnt * p) >> 2, hi = (cnt * (p + 1)) >> 2;
    for (int k = lo + tid; k < hi; k += 1024) {
        unsigned ent = g_bkt[s * BKTCAP + k];
        int i = (int)(ent >> 2);
        int e = (int)(ent & 3u);
        uint4 pw = g_pair[2 * i + (e >> 1)];
        int row = (e & 1) ? (int)(pw.x >> 16) : (int)(pw.x & 0xFFFFu);
        float px = __uint_as_float((e & 1) ? pw.z : pw.y);
        Meta m = g_meta[i];
        float ah = px * m.whv.x, av = px * m.whv.y;
        int base = (row >> 6) * 1024;      // in-slab row = row/64
        unsigned c0 = m.cols.x & 0xFFFFu, c1 = m.cols.x >> 16;
        unsigned c2 = m.cols.y & 0xFFFFu, c3 = m.cols.y >> 16;
        int i0 = (c0 < 512u) ? base + 2 * (int)c0 : 8192;
        int i1 = (c1 < 512u) ? base + 2 * (int)c1 : 8192;
        int i2 = (c2 < 512u) ? base + 2 * (int)c2 : 8192;
        int i3 = (c3 < 512u) ? base + 2 * (int)c3 : 8192;
        unsafeAtomicAdd(&tile[i0],     ah * m.pys.x);
        unsafeAtomicAdd(&tile[i0 + 1], av * m.pys.x);
        unsafeAtomicAdd(&tile[i1],     ah * m.pys.y);
        unsafeAtomicAdd(&tile[i1 + 1], av * m.pys.y);
        unsafeAtomicAdd(&tile[i2],     ah * m.pys.z);
        unsafeAtomicAdd(&tile[i2 + 1], av * m.pys.z);
        unsafeAtomicAdd(&tile[i3],     ah * m.pys.w);
        unsafeAtomicAdd(&tile[i3 + 1], av * m.pys.w);
    }
    __syncthreads();

    // y-scan: 8 waves, wave r scans tile row r as float2 (H,V), carry chain
    int wid = tid >> 6, lane = tid & 63;
    if (wid < 8) {
        float2* rowp = (float2*)&tile[wid * 1024];
        float cx = 0.0f, cy = 0.0f;
        for (int ch = 0; ch < 8; ++ch) {
            float2 v = rowp[ch * 64 + lane];
#pragma unroll
            for (int off = 1; off < 64; off <<= 1) {
                float tx = __shfl_up(v.x, off);
                float ty = __shfl_up(v.y, off);
                if (lane >= off) { v.x += tx; v.y += ty; }
            }
            v.x += cx; v.y += cy;
            rowp[ch * 64 + lane] = v;
            cx = __shfl(v.x, 63); cy = __shfl(v.y, 63);
        }
    }
    __syncthreads();
    // Un-permute on write: tile row rr -> global row (rr<<6)|s
    int dstp = p * 524288 + (s << 10);
#pragma unroll
    for (int k = 0; k < 8; ++k) {
        int idx = tid + k * 1024;
        int rr = idx >> 10, cc = idx & 1023;
        g_part[dstp + (rr << 16) + cc] = tile[idx];
    }
}

// 64 blocks, block b owns output cols y in [8b, 8b+8). Part-merge + y-blur
// (shfl) -> LDS; per-wave x-scan + in-register x-blur; map/counts; ticket.
__global__ __launch_bounds__(1024) void k_finish(float* __restrict__ out,
                                                 int* __restrict__ cnt2,
                                                 int* __restrict__ tick) {
    __shared__ float sB[16 * 512];
    int tid = threadIdx.x;
    int b = blockIdx.x;
    int lane = tid & 63;
    int c20 = tid & 31;
    int xg = tid >> 5;
    int jj = (c20 < 10) ? c20 : c20 - 10;
    int cy = 8 * b - 1 + jj;
    if (cy < 0) cy = 1;
    if (cy > 511) cy = 510;
    int map = (c20 < 10) ? 0 : 1;
    int gcol = 2 * cy + map;                // interleaved column
    const float kw  = expf(-0.5f / 1024.0f);
    const float k1n = 1.0f / (1.0f + 2.0f * kw);
    const float k0n = kw * k1n;
    const float scale = 262144.0f / 50000.0f;
    bool active = c20 < 20;
    int t8  = (c20 < 10) ? c20 - 1 : c20 - 11;

    for (int xo = 0; xo < 16; ++xo) {
        int x = xo * 32 + xg;
        float v = 0.0f;
        if (active) {
            int base = x * 1024 + gcol;
#pragma unroll
            for (int p = 0; p < NPARTS; ++p) v += g_part[p * 524288 + base];
        }
        float vm = __shfl(v, lane - 1);
        float vp = __shfl(v, lane + 1);
        float yb = (k0n * (vm + vp) + k1n * v) * scale;
        if (t8 >= 0 && t8 < 8) sB[(map * 8 + t8) * 512 + x] = yb;
    }
    __syncthreads();

    int w = tid >> 6;
    float s0,s1,s2,s3,s4,s5,s6,s7;
    {
        float4 a  = *(float4*)&sB[w * 512 + lane * 8];
        float4 bq = *(float4*)&sB[w * 512 + lane * 8 + 4];
        s0 = a.x; s1 = s0 + a.y; s2 = s1 + a.z; s3 = s2 + a.w;
        s4 = s3 + bq.x; s5 = s4 + bq.y; s6 = s5 + bq.z; s7 = s6 + bq.w;
        float tot = s7;
#pragma unroll
        for (int off = 1; off < 64; off <<= 1) {
            float tv = __shfl_up(tot, off);
            if (lane >= off) tot += tv;
        }
        float e = tot - s7;
        s0 += e; s1 += e; s2 += e; s3 += e; s4 += e; s5 += e; s6 += e; s7 += e;
    }
    {
        float prev = __shfl(s7, lane - 1);
        float next = __shfl(s0, lane + 1);
        float pm = (lane == 0) ? s1 : prev;
        float nx = (lane == 63) ? s6 : next;
        float b0 = k0n * (pm + s1) + k1n * s0;
        float b1 = k0n * (s0 + s2) + k1n * s1;
        float b2 = k0n * (s1 + s3) + k1n * s2;
        float b3 = k0n * (s2 + s4) + k1n * s3;
        float b4 = k0n * (s3 + s5) + k1n * s4;
        float b5 = k0n * (s4 + s6) + k1n * s5;
        float b6 = k0n * (s5 + s7) + k1n * s6;
        float b7 = k0n * (s6 + nx) + k1n * s7;
        float* row = &sB[w * 512 + lane * 8];
        row[0]=b0; row[1]=b1; row[2]=b2; row[3]=b3;
        row[4]=b4; row[5]=b5; row[6]=b6; row[7]=b7;
    }
    __syncthreads();

    int x = tid >> 1, qh = (tid & 1) * 4;
    float4 o;
    int ch = 0, cv = 0;
#pragma unroll
    for (int k = 0; k < 4; ++k) {
        int tt = qh + k;
        float hv = sB[tt * 512 + x];
        float vv = sB[(8 + tt) * 512 + x];
        ((float*)&o)[k] = fmaxf(fabsf(hv), fabsf(vv));
        ch += (hv > 1.0f); cv += (vv > 1.0f);
    }
    *(float4*)&out[x * 512 + 8 * b + qh] = o;
#pragma unroll
    for (int off = 32; off > 0; off >>= 1) {
        ch += __shfl_down(ch, off);
        cv += __shfl_down(cv, off);
    }
    __shared__ int scnt[2];
    if (tid < 2) scnt[tid] = 0;
    __syncthreads();
    if (lane == 0) { atomicAdd(&scnt[0], ch); atomicAdd(&scnt[1], cv); }
    __syncthreads();
    if (tid == 0) {
        atomicAdd(&cnt2[0], scnt[0]);
        atomicAdd(&cnt2[1], scnt[1]);
        __threadfence();
        int old = atomicAdd(tick, 1);
        if (old == 63) {
            __threadfence();
            int h = cnt2[0], v = cnt2[1];
            out[262144] = (float)((h > v) ? h : v);   // max_overflow
            out[262145] = (float)(h + v);             // total_overflow
        }
    }
}

extern "C" void kernel_launch(void* const* d_in, const int* in_sizes, int n_in,
                              void* d_out, int out_size, void* d_ws, size_t ws_size,
                              hipStream_t stream) {
    const float* pos     = (const float*)d_in[0];
    const float* pin_pos = (const float*)d_in[1];
    const float* nsx     = (const float*)d_in[2];
    const float* nsy     = (const float*)d_in[3];
    const float* nw      = (const float*)d_in[4];
    const int*   fnp     = (const int*)d_in[5];
    const int*   mid     = (const int*)d_in[6];
    int nm = in_sizes[6];
    float* out = (float*)d_out;
    unsigned* bcnt = (unsigned*)d_ws;
    int* cnt2 = (int*)((char*)d_ws + 256);
    int* tick = (int*)((char*)d_ws + 264);

    hipMemsetAsync(d_ws, 0, 512, stream);
    hipLaunchKernelGGL(k_bbox,    dim3(NBBLK), dim3(1024), 0, stream,
                       pos, pin_pos, nsx, nsy, nw, fnp, mid, nm, bcnt);
    hipLaunchKernelGGL(k_deposit, dim3(256), dim3(1024), 0, stream, bcnt);
    hipLaunchKernelGGL(k_finish,  dim3(64), dim3(1024), 0, stream, out, cnt2, tick);
}

// Round 10
// 63.620 us; speedup vs baseline: 1.6173x; 1.0720x over previous
//
#include <hip/hip_runtime.h>

#define N_NETS  131072
#define N_PINS  (N_NETS * 4)
#define N_NODES 55000
#define NRECMAX (N_NETS + 128)     // nets + macro slots (96 used)
#define NBBLK   129                // ceil(NRECMAX/1024)
#define NPARTS  4
#define CELLCAP 160                // per-(slab,block) cell cap (Poisson mean ~56)

struct __align__(16) Meta { uint2 cols; float2 whv; float4 pys; };  // 32B

// Per-record deposit data
__device__ uint4 g_pair[NRECMAX * 2];  // {roww(lo16=r0,hi16=r0+1), px0, px1, pad}
__device__ Meta  g_meta[NRECMAX];
// Deterministic bucket cells: [slab][bbox-block][CELLCAP], counts [slab][block]
__device__ unsigned short g_cellcnt[64 * NBBLK];
__device__ unsigned g_cell[64 * NBBLK * CELLCAP];
__device__ float g_part[NPARTS * 512 * 1024];   // per-part y-scanned tiles
__device__ int   g_cnt2[2];
__device__ int   g_tick;

__global__ __launch_bounds__(1024) void k_bbox(
    const float* __restrict__ pos, const float* __restrict__ pin_pos,
    const float* __restrict__ nsx, const float* __restrict__ nsy,
    const float* __restrict__ nw,  const int* __restrict__ fnp,
    const int* __restrict__ mid, int nm)
{
    __shared__ unsigned s_stage[64 * CELLCAP];   // 40 KB
    __shared__ int s_cnt[64];
    int tid = threadIdx.x;
    int b = blockIdx.x;
    int t = b * 1024 + tid;
    if (b == 0 && tid == 0) { g_cnt2[0] = 0; g_cnt2[1] = 0; g_tick = 0; }
    if (tid < 64) s_cnt[tid] = 0;
    __syncthreads();

    auto append = [&](int s, unsigned ent) {
        int off = atomicAdd(&s_cnt[s], 1);
        if (off < CELLCAP) s_stage[s * CELLCAP + off] = ent;
    };

    bool valid = t < N_NETS + nm && t < NRECMAX;
    if (valid) {
        float xmin, xmax, ymin, ymax, wh, wv;
        if (t < N_NETS) {
            int4 p = ((const int4*)fnp)[t];
            float x0 = pin_pos[p.x], x1 = pin_pos[p.y], x2 = pin_pos[p.z], x3 = pin_pos[p.w];
            float y0 = pin_pos[N_PINS + p.x], y1 = pin_pos[N_PINS + p.y];
            float y2 = pin_pos[N_PINS + p.z], y3 = pin_pos[N_PINS + p.w];
            xmin = fminf(fminf(x0, x1), fminf(x2, x3));
            xmax = fmaxf(fmaxf(x0, x1), fmaxf(x2, x3));
            ymin = fminf(fminf(y0, y1), fminf(y2, y3));
            ymax = fmaxf(fmaxf(y0, y1), fmaxf(y2, y3));
            float w = nw[t];
            wh = w / (ymax - ymin);
            wv = w / (xmax - xmin);
        } else {
            int idx = mid[t - N_NETS];
            xmin = pos[idx]; ymin = pos[N_NODES + idx];
            float sx = nsx[idx], sy = nsy[idx];
            xmax = xmin + sx; ymax = ymin + sy;
            wh = wv = 10.0f / (sx * sy);
        }
        const float B = 1.0f / 512.0f;
        int xl = min(max((int)(xmin * 512.0f), 0), 511);
        int xh = min(max((int)(xmax * 512.0f), 0), 511);
        int yl = min(max((int)(ymin * 512.0f), 0), 511);
        int yh = min(max((int)(ymax * 512.0f), 0), 511);
        g_pair[2 * t] = make_uint4(
            (unsigned)xl | ((unsigned)(xl + 1) << 16),
            __float_as_uint((xl + 1) * B - xmin),
            __float_as_uint(xmin - xl * B), 0u);
        g_pair[2 * t + 1] = make_uint4(
            (unsigned)xh | ((unsigned)(xh + 1) << 16),
            __float_as_uint(xmax - (xh + 1) * B),
            __float_as_uint(xh * B - xmax), 0u);
        Meta m;
        m.cols = make_uint2((unsigned)yl | ((unsigned)(yl + 1) << 16),
                            (unsigned)yh | ((unsigned)(yh + 1) << 16));
        m.whv = make_float2(wh, wv);
        m.pys = make_float4((yl + 1) * B - ymin, ymin - yl * B,
                            ymax - (yh + 1) * B, yh * B - ymax);
        g_meta[t] = m;
        // Row-permuted slab assignment: slab(r) = r & 63 (uniform load).
        append(xl & 63,        ((unsigned)t << 2) | 0u);
        if (xl + 1 < 512) append((xl + 1) & 63, ((unsigned)t << 2) | 1u);
        append(xh & 63,        ((unsigned)t << 2) | 2u);
        if (xh + 1 < 512) append((xh + 1) & 63, ((unsigned)t << 2) | 3u);
    }
    __syncthreads();
    if (tid < 64) g_cellcnt[tid * NBBLK + b] = (unsigned short)min(s_cnt[tid], CELLCAP);
    int wid = tid >> 6, lane = tid & 63;
    for (int s = wid; s < 64; s += 16) {
        int n = min(s_cnt[s], CELLCAP);
        unsigned* dst = &g_cell[(unsigned)(s * NBBLK + b) * CELLCAP];
        for (int k = lane; k < n; k += 64) dst[k] = s_stage[s * CELLCAP + k];
    }
}

// 256 blocks = 64 slabs x 4 parts (slab-major). Part p consumes bbox-blocks
// [lob,hib) of its slab via wave-scan prefix + LDS binary search (no atomics).
__global__ __launch_bounds__(1024) void k_deposit() {
    __shared__ float tile[8706];           // 8 rows x 1024 interleaved + dummy @8192
    __shared__ int s_pref[64];
    __shared__ int s_total;
    int tid = threadIdx.x;
    int s = blockIdx.x >> 2, p = blockIdx.x & 3;
#pragma unroll
    for (int k = tid; k < 8706; k += 1024) tile[k] = 0.0f;

    int lob = (NBBLK * p) >> 2, hib = (NBBLK * (p + 1)) >> 2;
    int nb = hib - lob;                    // 32 or 33
    if (tid < 64) {
        int c = (tid < nb) ? (int)g_cellcnt[s * NBBLK + lob + tid] : 0;
        int v = c;
#pragma unroll
        for (int off = 1; off < 64; off <<= 1) {
            int tv = __shfl_up(v, off);
            if (tid >= off) v += tv;
        }
        s_pref[tid] = v - c;               // exclusive prefix
        if (tid == 63) s_total = v;
    }
    __syncthreads();

    int total = s_total;
    for (int k = tid; k < total; k += 1024) {
        int loJ = 0, hiJ = 63;             // largest j with s_pref[j] <= k
#pragma unroll
        for (int st = 0; st < 6; ++st) {
            int mid = (loJ + hiJ + 1) >> 1;
            if (s_pref[mid] <= k) loJ = mid; else hiJ = mid - 1;
        }
        int bb = lob + loJ;
        int idx = k - s_pref[loJ];
        unsigned ent = g_cell[(unsigned)(s * NBBLK + bb) * CELLCAP + idx];
        int i = (int)(ent >> 2);
        int e = (int)(ent & 3u);
        uint4 pw = g_pair[2 * i + (e >> 1)];
        int row = (e & 1) ? (int)(pw.x >> 16) : (int)(pw.x & 0xFFFFu);
        float px = __uint_as_float((e & 1) ? pw.z : pw.y);
        Meta m = g_meta[i];
        float ah = px * m.whv.x, av = px * m.whv.y;
        int base = (row >> 6) * 1024;      // in-slab row = row/64
        unsigned c0 = m.cols.x & 0xFFFFu, c1 = m.cols.x >> 16;
        unsigned c2 = m.cols.y & 0xFFFFu, c3 = m.cols.y >> 16;
        int i0 = (c0 < 512u) ? base + 2 * (int)c0 : 8192;
        int i1 = (c1 < 512u) ? base + 2 * (int)c1 : 8192;
        int i2 = (c2 < 512u) ? base + 2 * (int)c2 : 8192;
        int i3 = (c3 < 512u) ? base + 2 * (int)c3 : 8192;
        unsafeAtomicAdd(&tile[i0],     ah * m.pys.x);
        unsafeAtomicAdd(&tile[i0 + 1], av * m.pys.x);
        unsafeAtomicAdd(&tile[i1],     ah * m.pys.y);
        unsafeAtomicAdd(&tile[i1 + 1], av * m.pys.y);
        unsafeAtomicAdd(&tile[i2],     ah * m.pys.z);
        unsafeAtomicAdd(&tile[i2 + 1], av * m.pys.z);
        unsafeAtomicAdd(&tile[i3],     ah * m.pys.w);
        unsafeAtomicAdd(&tile[i3 + 1], av * m.pys.w);
    }
    __syncthreads();

    // y-scan: 8 waves, wave r scans tile row r as float2 (H,V), carry chain
    int wid = tid >> 6, lane = tid & 63;
    if (wid < 8) {
        float2* rowp = (float2*)&tile[wid * 1024];
        float cx = 0.0f, cy = 0.0f;
        for (int ch = 0; ch < 8; ++ch) {
            float2 v = rowp[ch * 64 + lane];
#pragma unroll
            for (int off = 1; off < 64; off <<= 1) {
                float tx = __shfl_up(v.x, off);
                float ty = __shfl_up(v.y, off);
                if (lane >= off) { v.x += tx; v.y += ty; }
            }
            v.x += cx; v.y += cy;
            rowp[ch * 64 + lane] = v;
            cx = __shfl(v.x, 63); cy = __shfl(v.y, 63);
        }
    }
    __syncthreads();
    // Un-permute on write: tile row rr -> global row (rr<<6)|s
    int dstp = p * 524288 + (s << 10);
#pragma unroll
    for (int k = 0; k < 8; ++k) {
        int idx = tid + k * 1024;
        int rr = idx >> 10, cc = idx & 1023;
        g_part[dstp + (rr << 16) + cc] = tile[idx];
    }
}

// 64 blocks, block b owns output cols y in [8b, 8b+8). Part-merge + y-blur
// (shfl) -> LDS; per-wave x-scan + in-register x-blur; map/counts; ticket.
__global__ __launch_bounds__(1024) void k_finish(float* __restrict__ out) {
    __shared__ float sB[16 * 512];
    int tid = threadIdx.x;
    int b = blockIdx.x;
    int lane = tid & 63;
    int c20 = tid & 31;
    int xg = tid >> 5;
    int jj = (c20 < 10) ? c20 : c20 - 10;
    int cy = 8 * b - 1 + jj;
    if (cy < 0) cy = 1;
    if (cy > 511) cy = 510;
    int map = (c20 < 10) ? 0 : 1;
    int gcol = 2 * cy + map;                // interleaved column
    const float kw  = expf(-0.5f / 1024.0f);
    const float k1n = 1.0f / (1.0f + 2.0f * kw);
    const float k0n = kw * k1n;
    const float scale = 262144.0f / 50000.0f;
    bool active = c20 < 20;
    int t8  = (c20 < 10) ? c20 - 1 : c20 - 11;

    for (int xo = 0; xo < 16; ++xo) {
        int x = xo * 32 + xg;
        float v = 0.0f;
        if (active) {
            int base = x * 1024 + gcol;
#pragma unroll
            for (int p = 0; p < NPARTS; ++p) v += g_part[p * 524288 + base];
        }
        float vm = __shfl(v, lane - 1);
        float vp = __shfl(v, lane + 1);
        float yb = (k0n * (vm + vp) + k1n * v) * scale;
        if (t8 >= 0 && t8 < 8) sB[(map * 8 + t8) * 512 + x] = yb;
    }
    __syncthreads();

    int w = tid >> 6;
    float s0,s1,s2,s3,s4,s5,s6,s7;
    {
        float4 a  = *(float4*)&sB[w * 512 + lane * 8];
        float4 bq = *(float4*)&sB[w * 512 + lane * 8 + 4];
        s0 = a.x; s1 = s0 + a.y; s2 = s1 + a.z; s3 = s2 + a.w;
        s4 = s3 + bq.x; s5 = s4 + bq.y; s6 = s5 + bq.z; s7 = s6 + bq.w;
        float tot = s7;
#pragma unroll
        for (int off = 1; off < 64; off <<= 1) {
            float tv = __shfl_up(tot, off);
            if (lane >= off) tot += tv;
        }
        float e = tot - s7;
        s0 += e; s1 += e; s2 += e; s3 += e; s4 += e; s5 += e; s6 += e; s7 += e;
    }
    {
        float prev = __shfl(s7, lane - 1);
        float next = __shfl(s0, lane + 1);
        float pm = (lane == 0) ? s1 : prev;
        float nx = (lane == 63) ? s6 : next;
        float b0 = k0n * (pm + s1) + k1n * s0;
        float b1 = k0n * (s0 + s2) + k1n * s1;
        float b2 = k0n * (s1 + s3) + k1n * s2;
        float b3 = k0n * (s2 + s4) + k1n * s3;
        float b4 = k0n * (s3 + s5) + k1n * s4;
        float b5 = k0n * (s4 + s6) + k1n * s5;
        float b6 = k0n * (s5 + s7) + k1n * s6;
        float b7 = k0n * (s6 + nx) + k1n * s7;
        float* row = &sB[w * 512 + lane * 8];
        row[0]=b0; row[1]=b1; row[2]=b2; row[3]=b3;
        row[4]=b4; row[5]=b5; row[6]=b6; row[7]=b7;
    }
    __syncthreads();

    int x = tid >> 1, qh = (tid & 1) * 4;
    float4 o;
    int ch = 0, cv = 0;
#pragma unroll
    for (int k = 0; k < 4; ++k) {
        int tt = qh + k;
        float hv = sB[tt * 512 + x];
        float vv = sB[(8 + tt) * 512 + x];
        ((float*)&o)[k] = fmaxf(fabsf(hv), fabsf(vv));
        ch += (hv > 1.0f); cv += (vv > 1.0f);
    }
    *(float4*)&out[x * 512 + 8 * b + qh] = o;
#pragma unroll
    for (int off = 32; off > 0; off >>= 1) {
        ch += __shfl_down(ch, off);
        cv += __shfl_down(cv, off);
    }
    __shared__ int scnt[2];
    if (tid < 2) scnt[tid] = 0;
    __syncthreads();
    if (lane == 0) { atomicAdd(&scnt[0], ch); atomicAdd(&scnt[1], cv); }
    __syncthreads();
    if (tid == 0) {
        atomicAdd(&g_cnt2[0], scnt[0]);
        atomicAdd(&g_cnt2[1], scnt[1]);
        __threadfence();
        int old = atomicAdd(&g_tick, 1);
        if (old == 63) {
            __threadfence();
            int h = g_cnt2[0], v = g_cnt2[1];
            out[262144] = (float)((h > v) ? h : v);   // max_overflow
            out[262145] = (float)(h + v);             // total_overflow
        }
    }
}

extern "C" void kernel_launch(void* const* d_in, const int* in_sizes, int n_in,
                              void* d_out, int out_size, void* d_ws, size_t ws_size,
                              hipStream_t stream) {
    const float* pos     = (const float*)d_in[0];
    const float* pin_pos = (const float*)d_in[1];
    const float* nsx     = (const float*)d_in[2];
    const float* nsy     = (const float*)d_in[3];
    const float* nw      = (const float*)d_in[4];
    const int*   fnp     = (const int*)d_in[5];
    const int*   mid     = (const int*)d_in[6];
    int nm = in_sizes[6];
    float* out = (float*)d_out;

    hipLaunchKernelGGL(k_bbox,    dim3(NBBLK), dim3(1024), 0, stream,
                       pos, pin_pos, nsx, nsy, nw, fnp, mid, nm);
    hipLaunchKernelGGL(k_deposit, dim3(256), dim3(1024), 0, stream);
    hipLaunchKernelGGL(k_finish,  dim3(64), dim3(1024), 0, stream, out);
}